// Round 8
// baseline (134.184 us; speedup 1.0000x reference)
//
#include <hip/hip_runtime.h>

// MultiheadAttention fused, v6.
// prep: x->f16, W deinterleave, bias deinterleave.
// proj: 128x128x64 LDS GEMM; Q channel pre-scaled by log2(e) (exp2-domain softmax).
// attn: cross-tile pipelined flash attention — QK^T(t+1) overlaps softmax(t)+PV(t);
//       P transpose in-register via __shfl (no LDS roundtrip / no mid-tile drain).
// B=2 H=8 S=2048 E=64 F=512. f16 MFMA internally.

using half4v = __attribute__((ext_vector_type(4))) _Float16;
using half8  = __attribute__((ext_vector_type(8))) _Float16;
using f32x4  = __attribute__((ext_vector_type(4))) float;
using float4v = __attribute__((ext_vector_type(4))) float;
using uint4v = __attribute__((ext_vector_type(4))) unsigned int;

constexpr int BN = 2, HN = 8, SN = 2048, EN = 64, FN = 512;
constexpr size_t T_ELEMS = (size_t)BN * HN * SN * EN;      // 2M per tensor
constexpr float LOG2E = 1.4426950408889634f;

constexpr size_t WD_BYTES = (size_t)1536 * 512 * 2;             // 1.5 MB
constexpr size_t BPN_OFF  = WD_BYTES;
constexpr size_t X16_OFF  = BPN_OFF + 1536 * 4;
constexpr size_t X16_BYTES = (size_t)4096 * 512 * 2;            // 4 MB
constexpr size_t VT_OFF   = X16_OFF + X16_BYTES;
constexpr size_t VT_BYTES = T_ELEMS * 2;                        // 4 MB
constexpr size_t QKV_OFF  = VT_OFF + VT_BYTES;

__device__ inline unsigned int pack2h(float a, float b) {
  auto h = __builtin_amdgcn_cvt_pkrtz(a, b);
  return __builtin_bit_cast(unsigned int, h);
}

__device__ __forceinline__ void async_copy16(void* lds, const void* g) {
  __builtin_amdgcn_global_load_lds(
      (const __attribute__((address_space(1))) unsigned int*)g,
      (__attribute__((address_space(3))) unsigned int*)lds, 16, 0, 0);
}

// ---------------- kernel 1: prep
__global__ __launch_bounds__(256) void prep_kernel(
    const float* __restrict__ x, const float* __restrict__ W,
    const float* __restrict__ bias, _Float16* __restrict__ x16,
    _Float16* __restrict__ Wd, float* __restrict__ bpn) {
  int t = blockIdx.x * 256 + threadIdx.x;          // 262144 threads
  const float4v* src = (const float4v*)(x + (size_t)t * 8);
  float4v a = src[0], b = src[1];
  half8 o;
  #pragma unroll
  for (int i = 0; i < 4; ++i) { o[i] = (_Float16)a[i]; o[4 + i] = (_Float16)b[i]; }
  *(half8*)(x16 + (size_t)t * 8) = o;

  if (t < 1536 * 64) {                             // Wd gather
    int n = t >> 6, cc = t & 63, fb = cc * 8;
    int ch = n >> 6, e = n & 63, c = ch >> 3, h = ch & 7;
    int j = e * 24 + h * 3 + c;
    half8 w;
    #pragma unroll
    for (int i = 0; i < 8; ++i) w[i] = (_Float16)W[(size_t)(fb + i) * 1536 + j];
    *(half8*)(Wd + (size_t)n * 512 + fb) = w;
  }
  if (t < 1536) {
    int ch = t >> 6, e = t & 63, c = ch >> 3, h = ch & 7;
    bpn[t] = bias[e * 24 + h * 3 + c];
  }
}

// ---------------- kernel 2: proj GEMM. C[4096][1536] = x16 @ Wd^T + bpn.
__global__ __launch_bounds__(256, 2) void proj_kernel(
    const _Float16* __restrict__ x16, const _Float16* __restrict__ Wd,
    const float* __restrict__ bpn, _Float16* __restrict__ qkv,
    _Float16* __restrict__ vt) {
  __shared__ __align__(16) char smem[65536];   // A0,A1,B0,B1 @ 0,16K,32K,48K

  int tid = threadIdx.x;
  int wave = tid >> 6, lane = tid & 63;
  int q16 = lane & 15, g = lane >> 4;
  int wm = wave >> 1, wn = wave & 1;
  int gm_blk = blockIdx.x * 128, gn_blk = blockIdx.y * 128;

  f32x4 acc[4][4] = {};

  auto stage = [&](int c, int ks) {
    char* Ab = smem + c * 16384;
    char* Bb = smem + 32768 + c * 16384;
    int k0 = ks * 64;
    #pragma unroll
    for (int ii = 0; ii < 4; ++ii) {
      int qq = tid + 256 * ii;
      int row = qq >> 3, cc = qq & 7;
      int sc = (cc ^ (row & 7)) * 8;
      async_copy16(Ab + qq * 16, x16 + (size_t)(gm_blk + row) * 512 + k0 + sc);
      async_copy16(Bb + qq * 16, Wd + (size_t)(gn_blk + row) * 512 + k0 + sc);
    }
  };

  auto compute = [&](int c) {
    const char* Ab = smem + c * 16384;
    const char* Bb = smem + 32768 + c * 16384;
    #pragma unroll
    for (int kh = 0; kh < 2; ++kh) {
      half8 af[4], bf[4];
      #pragma unroll
      for (int mt = 0; mt < 4; ++mt) {
        int m = wm * 64 + mt * 16 + q16;
        af[mt] = *(const half8*)(Ab + m * 128 + ((kh * 64 + g * 16) ^ ((m & 7) << 4)));
      }
      #pragma unroll
      for (int nt = 0; nt < 4; ++nt) {
        int n = wn * 64 + nt * 16 + q16;
        bf[nt] = *(const half8*)(Bb + n * 128 + ((kh * 64 + g * 16) ^ ((n & 7) << 4)));
      }
      __builtin_amdgcn_s_setprio(1);
      #pragma unroll
      for (int mt = 0; mt < 4; ++mt)
        #pragma unroll
        for (int nt = 0; nt < 4; ++nt)
          acc[mt][nt] = __builtin_amdgcn_mfma_f32_16x16x32_f16(af[mt], bf[nt], acc[mt][nt], 0, 0, 0);
      __builtin_amdgcn_s_setprio(0);
    }
  };

  stage(0, 0);
  #pragma unroll
  for (int ks = 0; ks < 8; ++ks) {
    int cur = ks & 1;
    __syncthreads();
    if (ks + 1 < 8) {
      stage(cur ^ 1, ks + 1);
      asm volatile("s_waitcnt vmcnt(8)" ::: "memory");
    } else {
      asm volatile("s_waitcnt vmcnt(0)" ::: "memory");
    }
    __syncthreads();
    compute(cur);
  }

  int gn0 = gn_blk + wn * 64;
  int ch = gn0 >> 6, c = ch >> 3, h = ch & 7;
  int gm0 = gm_blk + wm * 64;
  if (c < 2) {
    float qscale = (c == 0) ? LOG2E : 1.f;       // Q in log2(e) units (exp2 softmax)
    _Float16* dst = qkv + (size_t)c * T_ELEMS;
    #pragma unroll
    for (int nt = 0; nt < 4; ++nt) {
      int e = nt * 16 + q16;
      float bv = bpn[gn0 + nt * 16 + q16];
      #pragma unroll
      for (int mt = 0; mt < 4; ++mt)
        #pragma unroll
        for (int r = 0; r < 4; ++r) {
          int gm = gm0 + mt * 16 + g * 4 + r;
          int b = gm >> 11, s = gm & 2047;
          dst[((size_t)(b * HN + h) * SN + s) * EN + e] = (_Float16)((acc[mt][nt][r] + bv) * qscale);
        }
    }
  } else {
    #pragma unroll
    for (int nt = 0; nt < 4; ++nt) {
      int e = nt * 16 + q16;
      float bv = bpn[gn0 + nt * 16 + q16];
      #pragma unroll
      for (int mt = 0; mt < 4; ++mt) {
        int gm = gm0 + mt * 16 + g * 4;
        int b = gm >> 11, s = gm & 2047;
        half4v hv;
        #pragma unroll
        for (int r = 0; r < 4; ++r) hv[r] = (_Float16)(acc[mt][nt][r] + bv);
        *(half4v*)(vt + ((size_t)(b * HN + h) * EN + e) * SN + s) = hv;
      }
    }
  }
}

// ---------------- kernel 3: flash attention v6 (cross-tile pipelined).
// grid 512 = 16 bh x 32 q-blocks (64 rows); 4 waves x 16 q-rows; KVBLK=64;
// 3 LDS buffers, stage depth 1 tile; QK^T(t+1) overlaps softmax(t)+PV(t);
// P transpose via __shfl; exp2-domain softmax (Q pre-scaled).
__global__ __launch_bounds__(256, 2) void attn_kernel(
    const _Float16* __restrict__ q_ws, const _Float16* __restrict__ k_ws,
    const _Float16* __restrict__ vt_ws, float* __restrict__ out) {
  __shared__ __align__(16) char smem[49152];   // 3 bufs x (K 8K + V 8K)

  int bid = blockIdx.x;
  int lb = (bid & 7) * 64 + (bid >> 3);        // XCD swizzle
  int bh = lb >> 5, qblk = lb & 31;
  int wave = threadIdx.x >> 6, lane = threadIdx.x & 63;
  int q = lane & 15, g = lane >> 4;
  int q0 = qblk * 64 + wave * 16;

  const _Float16* qb  = q_ws  + ((size_t)bh * SN + q0) * EN;
  const _Float16* kb  = k_ws  + (size_t)bh * SN * EN;
  const _Float16* vtb = vt_ws + (size_t)bh * EN * SN;

  half8 qf[2];
  qf[0] = *(const half8*)(qb + (size_t)q * EN + g * 8);
  qf[1] = *(const half8*)(qb + (size_t)q * EN + 32 + g * 8);

  f32x4 o[4] = {};
  float m = -3e38f, l = 0.f;

  int sub = lane >> 3;
  int off8 = ((lane & 7) ^ sub) * 8;
  int lin = lane * 16;

  auto stage = [&](int c, int t) {   // 4 gload_lds per lane
    char* kbuf = smem + c * 16384;
    char* vbuf = kbuf + 8192;
    int kv = t * 64;
    #pragma unroll
    for (int ii = 0; ii < 2; ++ii) {
      int i = wave * 2 + ii;
      int row = i * 8 + sub;
      async_copy16(kbuf + i * 1024 + lin, kb + (size_t)(kv + row) * EN + off8);
      async_copy16(vbuf + i * 1024 + lin, vtb + (size_t)row * SN + kv + off8);
    }
  };

  int qx = (q & 7) << 4;
  int srcA = q + 32 * (g & 1);       // P-transpose shuffle sources
  int srcB = srcA + 16;
  bool hi = (g >> 1) != 0;

  auto qk_tile = [&](int c, f32x4 (&s)[4]) {
    const char* kbuf = smem + c * 16384;
    half8 kf[4][2];
    #pragma unroll
    for (int kt = 0; kt < 4; ++kt)
      #pragma unroll
      for (int eh = 0; eh < 2; ++eh)
        kf[kt][eh] = *(const half8*)(kbuf + ((((kt * 16 + q) * 128) + eh * 64 + g * 16) ^ qx));
    f32x4 z = {};
    __builtin_amdgcn_s_setprio(1);
    #pragma unroll
    for (int kt = 0; kt < 4; ++kt) {
      s[kt] = __builtin_amdgcn_mfma_f32_16x16x32_f16(kf[kt][0], qf[0], z, 0, 0, 0);
      s[kt] = __builtin_amdgcn_mfma_f32_16x16x32_f16(kf[kt][1], qf[1], s[kt], 0, 0, 0);
    }
    __builtin_amdgcn_s_setprio(0);
  };

  auto finish_pv = [&](f32x4 (&s)[4], int c) {
    const char* vbuf = smem + c * 16384 + 8192;
    half8 vf[4][2];
    #pragma unroll
    for (int et = 0; et < 4; ++et)
      #pragma unroll
      for (int kh = 0; kh < 2; ++kh)
        vf[et][kh] = *(const half8*)(vbuf + ((((et * 16 + q) * 128) + kh * 64 + g * 16) ^ qx));

    float mx = s[0][0];
    #pragma unroll
    for (int kt = 0; kt < 4; ++kt)
      #pragma unroll
      for (int r = 0; r < 4; ++r) mx = fmaxf(mx, s[kt][r]);
    mx = fmaxf(mx, __shfl_xor(mx, 16));
    mx = fmaxf(mx, __shfl_xor(mx, 32));
    if (!__all(mx <= m + 12.f)) {          // defer-max (log2 units)
      float mn = fmaxf(m, mx);
      float scl = exp2f(m - mn);
      m = mn;
      l *= scl;
      #pragma unroll
      for (int et = 0; et < 4; ++et)
        #pragma unroll
        for (int r = 0; r < 4; ++r) o[et][r] *= scl;
    }
    float ps = 0.f;
    unsigned w00, w01, w10, w11, w20, w21, w30, w31;
    {
      float p0, p1, p2, p3;
      p0 = exp2f(s[0][0] - m); p1 = exp2f(s[0][1] - m); p2 = exp2f(s[0][2] - m); p3 = exp2f(s[0][3] - m);
      ps += (p0 + p1) + (p2 + p3); w00 = pack2h(p0, p1); w01 = pack2h(p2, p3);
      p0 = exp2f(s[1][0] - m); p1 = exp2f(s[1][1] - m); p2 = exp2f(s[1][2] - m); p3 = exp2f(s[1][3] - m);
      ps += (p0 + p1) + (p2 + p3); w10 = pack2h(p0, p1); w11 = pack2h(p2, p3);
      p0 = exp2f(s[2][0] - m); p1 = exp2f(s[2][1] - m); p2 = exp2f(s[2][2] - m); p3 = exp2f(s[2][3] - m);
      ps += (p0 + p1) + (p2 + p3); w20 = pack2h(p0, p1); w21 = pack2h(p2, p3);
      p0 = exp2f(s[3][0] - m); p1 = exp2f(s[3][1] - m); p2 = exp2f(s[3][2] - m); p3 = exp2f(s[3][3] - m);
      ps += (p0 + p1) + (p2 + p3); w30 = pack2h(p0, p1); w31 = pack2h(p2, p3);
    }
    l += ps;
    // P^T gather: pf[kh] word layout {A:w[kt][0], A:w[kt][1], B:w[kt][0], B:w[kt][1]},
    // kt = 2kh + (g>>1); shuffle both kt candidates, cndmask-select.
    uint4v pv0, pv1;
    {
      unsigned xa0 = __shfl(w00, srcA), ya0 = __shfl(w10, srcA);
      unsigned xa1 = __shfl(w01, srcA), ya1 = __shfl(w11, srcA);
      unsigned xb0 = __shfl(w00, srcB), yb0 = __shfl(w10, srcB);
      unsigned xb1 = __shfl(w01, srcB), yb1 = __shfl(w11, srcB);
      pv0.x = hi ? ya0 : xa0; pv0.y = hi ? ya1 : xa1;
      pv0.z = hi ? yb0 : xb0; pv0.w = hi ? yb1 : xb1;
      unsigned za0 = __shfl(w20, srcA), ua0 = __shfl(w30, srcA);
      unsigned za1 = __shfl(w21, srcA), ua1 = __shfl(w31, srcA);
      unsigned zb0 = __shfl(w20, srcB), ub0 = __shfl(w30, srcB);
      unsigned zb1 = __shfl(w21, srcB), ub1 = __shfl(w31, srcB);
      pv1.x = hi ? ua0 : za0; pv1.y = hi ? ua1 : za1;
      pv1.z = hi ? ub0 : zb0; pv1.w = hi ? ub1 : zb1;
    }
    half8 pf0 = __builtin_bit_cast(half8, pv0);
    half8 pf1 = __builtin_bit_cast(half8, pv1);
    __builtin_amdgcn_s_setprio(1);
    #pragma unroll
    for (int et = 0; et < 4; ++et) {
      o[et] = __builtin_amdgcn_mfma_f32_16x16x32_f16(vf[et][0], pf0, o[et], 0, 0, 0);
      o[et] = __builtin_amdgcn_mfma_f32_16x16x32_f16(vf[et][1], pf1, o[et], 0, 0, 0);
    }
    __builtin_amdgcn_s_setprio(0);
  };

  f32x4 sA[4], sB[4];

  stage(0, 0);
  stage(1, 1);
  asm volatile("s_waitcnt vmcnt(4)" ::: "memory");   // own tile-0 landed
  __syncthreads();                                    // everyone's tile-0 landed
  qk_tile(0, sA);

  for (int t0 = 0; t0 < 30; t0 += 2) {
    asm volatile("s_waitcnt vmcnt(0)" ::: "memory");  // tile t0+1 landed (own)
    __syncthreads();                                   // everyone's; prev reads done
    stage((t0 + 2) % 3, t0 + 2);
    qk_tile((t0 + 1) % 3, sB);                         // QK(t0+1) overlaps softmax(t0)
    finish_pv(sA, t0 % 3);

    asm volatile("s_waitcnt vmcnt(0)" ::: "memory");
    __syncthreads();
    stage((t0 + 3) % 3, t0 + 3);
    qk_tile((t0 + 2) % 3, sA);
    finish_pv(sB, (t0 + 1) % 3);
  }
  // t = 30
  asm volatile("s_waitcnt vmcnt(0)" ::: "memory");
  __syncthreads();
  qk_tile(31 % 3, sB);
  finish_pv(sA, 30 % 3);
  // t = 31
  finish_pv(sB, 31 % 3);

  // epilogue (ow aliases buf0 region — barrier so no wave still reads it)
  __syncthreads();
  l += __shfl_xor(l, 16);
  l += __shfl_xor(l, 32);
  float rl = 1.f / l;
  int b = bh >> 3, h = bh & 7;
  float* ow = (float*)(smem + wave * 4096);
  #pragma unroll
  for (int et = 0; et < 4; ++et)
    #pragma unroll
    for (int r = 0; r < 4; ++r) {
      int e = et * 16 + g * 4 + r;
      ow[q * 64 + ((e + q * 4) & 63)] = o[et][r] * rl;
    }
  asm volatile("s_waitcnt lgkmcnt(0)" ::: "memory");
  __builtin_amdgcn_sched_barrier(0);
  #pragma unroll
  for (int qr = 0; qr < 16; ++qr) {
    float vvv = ow[qr * 64 + ((lane + qr * 4) & 63)];
    out[((size_t)b * SN + q0 + qr) * 512 + h * 64 + lane] = vvv;
  }
}

extern "C" void kernel_launch(void* const* d_in, const int* in_sizes, int n_in,
                              void* d_out, int out_size, void* d_ws, size_t ws_size,
                              hipStream_t stream) {
  const float* x    = (const float*)d_in[0];
  const float* W    = (const float*)d_in[1];
  const float* bias = (const float*)d_in[2];
  float* out = (float*)d_out;
  char* ws = (char*)d_ws;
  _Float16* Wd  = (_Float16*)(ws);
  float*    bpn = (float*)(ws + BPN_OFF);
  _Float16* x16 = (_Float16*)(ws + X16_OFF);
  _Float16* vt  = (_Float16*)(ws + VT_OFF);
  _Float16* qkv = (_Float16*)(ws + QKV_OFF);   // Q @0, K @T_ELEMS

  prep_kernel<<<1024, 256, 0, stream>>>(x, W, bias, x16, Wd, bpn);
  proj_kernel<<<dim3(32, 12), 256, 0, stream>>>(x16, Wd, bpn, qkv, vt);
  attn_kernel<<<512, 256, 0, stream>>>(qkv, qkv + T_ELEMS, vt, out);
}

// Round 9
// 127.211 us; speedup vs baseline: 1.0548x; 1.0548x over previous
//
#include <hip/hip_runtime.h>

// MultiheadAttention fused, v7.
// prep: x->f16, W deinterleave, bias deinterleave.
// proj: 128x128x64 LDS GEMM; Q channel pre-scaled by log2(e).
// attn: v4 structure (LDS P-transpose, triple-buffer, counted vmcnt) +
//       exp2 softmax + 8 waves/block (512 thr, grid 256, 4 waves/SIMD,
//       staging shared by 8 waves).
// B=2 H=8 S=2048 E=64 F=512. f16 MFMA internally.

using half4v = __attribute__((ext_vector_type(4))) _Float16;
using half8  = __attribute__((ext_vector_type(8))) _Float16;
using f32x4  = __attribute__((ext_vector_type(4))) float;
using float4v = __attribute__((ext_vector_type(4))) float;
using uint2v = __attribute__((ext_vector_type(2))) unsigned int;
using uint4v = __attribute__((ext_vector_type(4))) unsigned int;

constexpr int BN = 2, HN = 8, SN = 2048, EN = 64, FN = 512;
constexpr size_t T_ELEMS = (size_t)BN * HN * SN * EN;      // 2M per tensor
constexpr float LOG2E = 1.4426950408889634f;

constexpr size_t WD_BYTES = (size_t)1536 * 512 * 2;             // 1.5 MB
constexpr size_t BPN_OFF  = WD_BYTES;
constexpr size_t X16_OFF  = BPN_OFF + 1536 * 4;
constexpr size_t X16_BYTES = (size_t)4096 * 512 * 2;            // 4 MB
constexpr size_t VT_OFF   = X16_OFF + X16_BYTES;
constexpr size_t VT_BYTES = T_ELEMS * 2;                        // 4 MB
constexpr size_t QKV_OFF  = VT_OFF + VT_BYTES;

__device__ inline unsigned int pack2h(float a, float b) {
  auto h = __builtin_amdgcn_cvt_pkrtz(a, b);
  return __builtin_bit_cast(unsigned int, h);
}

__device__ __forceinline__ void async_copy16(void* lds, const void* g) {
  __builtin_amdgcn_global_load_lds(
      (const __attribute__((address_space(1))) unsigned int*)g,
      (__attribute__((address_space(3))) unsigned int*)lds, 16, 0, 0);
}

// ---------------- kernel 1: prep
__global__ __launch_bounds__(256) void prep_kernel(
    const float* __restrict__ x, const float* __restrict__ W,
    const float* __restrict__ bias, _Float16* __restrict__ x16,
    _Float16* __restrict__ Wd, float* __restrict__ bpn) {
  int t = blockIdx.x * 256 + threadIdx.x;          // 262144 threads
  const float4v* src = (const float4v*)(x + (size_t)t * 8);
  float4v a = src[0], b = src[1];
  half8 o;
  #pragma unroll
  for (int i = 0; i < 4; ++i) { o[i] = (_Float16)a[i]; o[4 + i] = (_Float16)b[i]; }
  *(half8*)(x16 + (size_t)t * 8) = o;

  if (t < 1536 * 64) {                             // Wd gather
    int n = t >> 6, cc = t & 63, fb = cc * 8;
    int ch = n >> 6, e = n & 63, c = ch >> 3, h = ch & 7;
    int j = e * 24 + h * 3 + c;
    half8 w;
    #pragma unroll
    for (int i = 0; i < 8; ++i) w[i] = (_Float16)W[(size_t)(fb + i) * 1536 + j];
    *(half8*)(Wd + (size_t)n * 512 + fb) = w;
  }
  if (t < 1536) {
    int ch = t >> 6, e = t & 63, c = ch >> 3, h = ch & 7;
    bpn[t] = bias[e * 24 + h * 3 + c];
  }
}

// ---------------- kernel 2: proj GEMM. C[4096][1536] = x16 @ Wd^T + bpn.
__global__ __launch_bounds__(256, 2) void proj_kernel(
    const _Float16* __restrict__ x16, const _Float16* __restrict__ Wd,
    const float* __restrict__ bpn, _Float16* __restrict__ qkv,
    _Float16* __restrict__ vt) {
  __shared__ __align__(16) char smem[65536];   // A0,A1,B0,B1 @ 0,16K,32K,48K

  int tid = threadIdx.x;
  int wave = tid >> 6, lane = tid & 63;
  int q16 = lane & 15, g = lane >> 4;
  int wm = wave >> 1, wn = wave & 1;
  int gm_blk = blockIdx.x * 128, gn_blk = blockIdx.y * 128;

  f32x4 acc[4][4] = {};

  auto stage = [&](int c, int ks) {
    char* Ab = smem + c * 16384;
    char* Bb = smem + 32768 + c * 16384;
    int k0 = ks * 64;
    #pragma unroll
    for (int ii = 0; ii < 4; ++ii) {
      int qq = tid + 256 * ii;
      int row = qq >> 3, cc = qq & 7;
      int sc = (cc ^ (row & 7)) * 8;
      async_copy16(Ab + qq * 16, x16 + (size_t)(gm_blk + row) * 512 + k0 + sc);
      async_copy16(Bb + qq * 16, Wd + (size_t)(gn_blk + row) * 512 + k0 + sc);
    }
  };

  auto compute = [&](int c) {
    const char* Ab = smem + c * 16384;
    const char* Bb = smem + 32768 + c * 16384;
    #pragma unroll
    for (int kh = 0; kh < 2; ++kh) {
      half8 af[4], bf[4];
      #pragma unroll
      for (int mt = 0; mt < 4; ++mt) {
        int m = wm * 64 + mt * 16 + q16;
        af[mt] = *(const half8*)(Ab + m * 128 + ((kh * 64 + g * 16) ^ ((m & 7) << 4)));
      }
      #pragma unroll
      for (int nt = 0; nt < 4; ++nt) {
        int n = wn * 64 + nt * 16 + q16;
        bf[nt] = *(const half8*)(Bb + n * 128 + ((kh * 64 + g * 16) ^ ((n & 7) << 4)));
      }
      __builtin_amdgcn_s_setprio(1);
      #pragma unroll
      for (int mt = 0; mt < 4; ++mt)
        #pragma unroll
        for (int nt = 0; nt < 4; ++nt)
          acc[mt][nt] = __builtin_amdgcn_mfma_f32_16x16x32_f16(af[mt], bf[nt], acc[mt][nt], 0, 0, 0);
      __builtin_amdgcn_s_setprio(0);
    }
  };

  stage(0, 0);
  #pragma unroll
  for (int ks = 0; ks < 8; ++ks) {
    int cur = ks & 1;
    __syncthreads();
    if (ks + 1 < 8) {
      stage(cur ^ 1, ks + 1);
      asm volatile("s_waitcnt vmcnt(8)" ::: "memory");
    } else {
      asm volatile("s_waitcnt vmcnt(0)" ::: "memory");
    }
    __syncthreads();
    compute(cur);
  }

  int gn0 = gn_blk + wn * 64;
  int ch = gn0 >> 6, c = ch >> 3, h = ch & 7;
  int gm0 = gm_blk + wm * 64;
  if (c < 2) {
    float qscale = (c == 0) ? LOG2E : 1.f;       // Q in log2(e) units (exp2 softmax)
    _Float16* dst = qkv + (size_t)c * T_ELEMS;
    #pragma unroll
    for (int nt = 0; nt < 4; ++nt) {
      int e = nt * 16 + q16;
      float bv = bpn[gn0 + nt * 16 + q16];
      #pragma unroll
      for (int mt = 0; mt < 4; ++mt)
        #pragma unroll
        for (int r = 0; r < 4; ++r) {
          int gm = gm0 + mt * 16 + g * 4 + r;
          int b = gm >> 11, s = gm & 2047;
          dst[((size_t)(b * HN + h) * SN + s) * EN + e] = (_Float16)((acc[mt][nt][r] + bv) * qscale);
        }
    }
  } else {
    #pragma unroll
    for (int nt = 0; nt < 4; ++nt) {
      int e = nt * 16 + q16;
      float bv = bpn[gn0 + nt * 16 + q16];
      #pragma unroll
      for (int mt = 0; mt < 4; ++mt) {
        int gm = gm0 + mt * 16 + g * 4;
        int b = gm >> 11, s = gm & 2047;
        half4v hv;
        #pragma unroll
        for (int r = 0; r < 4; ++r) hv[r] = (_Float16)(acc[mt][nt][r] + bv);
        *(half4v*)(vt + ((size_t)(b * HN + h) * EN + e) * SN + s) = hv;
      }
    }
  }
}

// ---------------- kernel 3: flash attention v7.
// grid 256 = 16 bh x 16 q-blocks (128 rows). 8 waves x 16 q-rows.
// Triple-buffered K/V LDS staging (shared by all 8 waves: 2 gload_lds/lane/tile),
// counted vmcnt(2), XOR swizzle, LDS P-transpose, exp2 softmax, defer-max.
__global__ __launch_bounds__(512, 4) void attn_kernel(
    const _Float16* __restrict__ q_ws, const _Float16* __restrict__ k_ws,
    const _Float16* __restrict__ vt_ws, float* __restrict__ out) {
  // [0,49152): 3 KV buffers (16 KB each: K @+0, V @+8192)
  // [49152,65536): per-wave P transpose (2 KB x 8)
  // epilogue: per-wave O transpose 4 KB at wave*4096 (aliases buf0/1/2)
  __shared__ __align__(16) char smem[65536];

  int bid = blockIdx.x;
  int lb = (bid & 7) * 32 + (bid >> 3);          // XCD swizzle (256 % 8 == 0)
  int bh = lb >> 4, qblk = lb & 15;
  int tid = threadIdx.x;
  int wave = tid >> 6, lane = tid & 63;
  int q = lane & 15, g = lane >> 4;
  int q0 = qblk * 128 + wave * 16;

  const _Float16* qb  = q_ws  + ((size_t)bh * SN + q0) * EN;
  const _Float16* kb  = k_ws  + (size_t)bh * SN * EN;
  const _Float16* vtb = vt_ws + (size_t)bh * EN * SN;

  half8 qf[2];
  qf[0] = *(const half8*)(qb + (size_t)q * EN + g * 8);
  qf[1] = *(const half8*)(qb + (size_t)q * EN + 32 + g * 8);

  f32x4 o[4] = {};                  // O^T: col=q, row e = et*16 + g*4 + r
  float m = -3e38f, l = 0.f;
  unsigned int* pw = (unsigned int*)(smem + 49152 + wave * 2048);

  // staging: 512 lanes cover K tile (64x128B) and V tile with one 16B copy each
  int srow = tid >> 3;                        // 0..63
  int soff8 = ((tid & 7) ^ (srow & 7)) * 8;   // inverse-swizzled source col (halves)
  int slin = tid * 16;                        // linear LDS dest

  auto stage = [&](int c, int t) {   // 2 gload_lds per lane
    char* kbuf = smem + c * 16384;
    char* vbuf = kbuf + 8192;
    int kv = t * 64;
    async_copy16(kbuf + slin, kb + (size_t)(kv + srow) * EN + soff8);
    async_copy16(vbuf + slin, vtb + (size_t)srow * SN + kv + soff8);
  };

  int qx = (q & 7) << 4;

  auto compute = [&](int c) {
    const char* kbuf = smem + c * 16384;
    const char* vbuf = kbuf + 8192;

    f32x4 s[4];
    f32x4 z = {};
    #pragma unroll
    for (int kt = 0; kt < 4; ++kt) {
      half8 kf0 = *(const half8*)(kbuf + ((((kt * 16 + q) * 128) + g * 16) ^ qx));
      half8 kf1 = *(const half8*)(kbuf + ((((kt * 16 + q) * 128) + 64 + g * 16) ^ qx));
      __builtin_amdgcn_s_setprio(1);
      s[kt] = __builtin_amdgcn_mfma_f32_16x16x32_f16(kf0, qf[0], z, 0, 0, 0);
      s[kt] = __builtin_amdgcn_mfma_f32_16x16x32_f16(kf1, qf[1], s[kt], 0, 0, 0);
      __builtin_amdgcn_s_setprio(0);
    }

    float mx = s[0][0];
    #pragma unroll
    for (int kt = 0; kt < 4; ++kt)
      #pragma unroll
      for (int r = 0; r < 4; ++r) mx = fmaxf(mx, s[kt][r]);
    mx = fmaxf(mx, __shfl_xor(mx, 16));
    mx = fmaxf(mx, __shfl_xor(mx, 32));
    if (!__all(mx <= m + 12.f)) {     // defer-max (log2 units)
      float mn = fmaxf(m, mx);
      float scl = exp2f(m - mn);
      m = mn;
      l *= scl;
      #pragma unroll
      for (int et = 0; et < 4; ++et)
        #pragma unroll
        for (int r = 0; r < 4; ++r) o[et][r] *= scl;
    }
    float ps = 0.f;
    #pragma unroll
    for (int kt = 0; kt < 4; ++kt) {
      float p0 = exp2f(s[kt][0] - m), p1 = exp2f(s[kt][1] - m);
      float p2 = exp2f(s[kt][2] - m), p3 = exp2f(s[kt][3] - m);
      ps += (p0 + p1) + (p2 + p3);
      uint2v wv;
      wv.x = pack2h(p0, p1);
      wv.y = pack2h(p2, p3);
      int w = kt * 8 + 2 * g;                  // chunk-rotated P^T transpose
      int phys = (((w >> 2) + q) & 7) * 4 + (w & 3);
      *(uint2v*)&pw[q * 32 + phys] = wv;
    }
    l += ps;
    asm volatile("s_waitcnt lgkmcnt(0)" ::: "memory");
    __builtin_amdgcn_sched_barrier(0);
    half8 pf[2];
    #pragma unroll
    for (int kh = 0; kh < 2; ++kh) {
      int cc = kh * 4 + g;
      uint4v tv = *(const uint4v*)&pw[q * 32 + ((cc + q) & 7) * 4];
      pf[kh] = __builtin_bit_cast(half8, tv);
    }
    __builtin_amdgcn_sched_barrier(0);
    #pragma unroll
    for (int et = 0; et < 4; ++et) {
      half8 vf0 = *(const half8*)(vbuf + ((((et * 16 + q) * 128) + g * 16) ^ qx));
      half8 vf1 = *(const half8*)(vbuf + ((((et * 16 + q) * 128) + 64 + g * 16) ^ qx));
      __builtin_amdgcn_s_setprio(1);
      o[et] = __builtin_amdgcn_mfma_f32_16x16x32_f16(vf0, pf[0], o[et], 0, 0, 0);
      o[et] = __builtin_amdgcn_mfma_f32_16x16x32_f16(vf1, pf[1], o[et], 0, 0, 0);
      __builtin_amdgcn_s_setprio(0);
    }
  };

  stage(0, 0);
  stage(1, 1);
  for (int t = 0; t < 31; ++t) {
    asm volatile("s_waitcnt vmcnt(2)" ::: "memory");   // tile-t loads landed (own)
    __syncthreads();                                    // => everyone's tile-t landed
    if (t + 2 < 32) stage((t + 2) % 3, t + 2);          // keep 2-4 loads in flight
    compute(t % 3);
  }
  asm volatile("s_waitcnt vmcnt(0)" ::: "memory");      // peeled last iter
  __syncthreads();
  compute(31 % 3);

  // epilogue: O^T -> per-wave LDS transpose (aliases bufs) -> coalesced stores
  __syncthreads();
  l += __shfl_xor(l, 16);
  l += __shfl_xor(l, 32);
  float rl = 1.f / l;
  int b = bh >> 3, h = bh & 7;
  float* ow = (float*)(smem + wave * 4096);
  #pragma unroll
  for (int et = 0; et < 4; ++et)
    #pragma unroll
    for (int r = 0; r < 4; ++r) {
      int e = et * 16 + g * 4 + r;
      ow[q * 64 + ((e + q * 4) & 63)] = o[et][r] * rl;
    }
  asm volatile("s_waitcnt lgkmcnt(0)" ::: "memory");
  __builtin_amdgcn_sched_barrier(0);
  #pragma unroll
  for (int qr = 0; qr < 16; ++qr) {
    float vvv = ow[qr * 64 + ((lane + qr * 4) & 63)];
    out[((size_t)b * SN + q0 + qr) * 512 + h * 64 + lane] = vvv;
  }
}

extern "C" void kernel_launch(void* const* d_in, const int* in_sizes, int n_in,
                              void* d_out, int out_size, void* d_ws, size_t ws_size,
                              hipStream_t stream) {
  const float* x    = (const float*)d_in[0];
  const float* W    = (const float*)d_in[1];
  const float* bias = (const float*)d_in[2];
  float* out = (float*)d_out;
  char* ws = (char*)d_ws;
  _Float16* Wd  = (_Float16*)(ws);
  float*    bpn = (float*)(ws + BPN_OFF);
  _Float16* x16 = (_Float16*)(ws + X16_OFF);
  _Float16* vt  = (_Float16*)(ws + VT_OFF);
  _Float16* qkv = (_Float16*)(ws + QKV_OFF);   // Q @0, K @T_ELEMS

  prep_kernel<<<1024, 256, 0, stream>>>(x, W, bias, x16, Wd, bpn);
  proj_kernel<<<dim3(32, 12), 256, 0, stream>>>(x16, Wd, bpn, qkv, vt);
  attn_kernel<<<256, 512, 0, stream>>>(qkv, qkv + T_ELEMS, vt, out);
}